// Round 1
// baseline (1142.586 us; speedup 1.0000x reference)
//
#include <hip/hip_runtime.h>
#include <cstddef>

#define BB 8
#define SS 2048
#define DD 512
#define MM (BB * SS)

typedef __attribute__((ext_vector_type(8))) short bf16x8;
typedef __attribute__((ext_vector_type(4))) float f32x4;
typedef __attribute__((ext_vector_type(4))) unsigned short u16x4;

__device__ __forceinline__ f32x4 mfma16(bf16x8 a, bf16x8 b, f32x4 c) {
  return __builtin_amdgcn_mfma_f32_16x16x32_bf16(a, b, c, 0, 0, 0);
}

// round-to-nearest-even fp32 -> bf16
__device__ __forceinline__ unsigned short f2bf(float f) {
  unsigned int u = __float_as_uint(f);
  u += 0x7fffu + ((u >> 16) & 1u);
  return (unsigned short)(u >> 16);
}

// ---------------- fp32 -> bf16 conversion, 4 elems/thread ----------------
__global__ void cvt_bf16_kernel(const float* __restrict__ in,
                                unsigned short* __restrict__ out, int n4) {
  int i = blockIdx.x * blockDim.x + threadIdx.x;
  if (i >= n4) return;
  f32x4 v = reinterpret_cast<const f32x4*>(in)[i];
  u16x4 o;
  o[0] = f2bf(v[0]);
  o[1] = f2bf(v[1]);
  o[2] = f2bf(v[2]);
  o[3] = f2bf(v[3]);
  reinterpret_cast<u16x4*>(out)[i] = o;
}

// ---------------- QKV projection GEMM: out[m][e] = sum_d X[m][d]*W[e][d] + b[e]
// X: [MM][DD] bf16 row-major, W: [DD][DD] bf16 row-major (torch Linear weight)
__global__ __launch_bounds__(256, 2) void qkv_gemm_kernel(
    const unsigned short* __restrict__ X, const unsigned short* __restrict__ W,
    const float* __restrict__ bias, unsigned short* __restrict__ out) {
  const int tid = threadIdx.x;
  const int w = tid >> 6;
  const int l = tid & 63;
  const int lr = l & 15;
  const int hi = l >> 4;
  const int m0 = blockIdx.x * 128 + (w >> 1) * 64;
  const int n0 = blockIdx.y * 128 + (w & 1) * 64;

  f32x4 acc[4][4];
#pragma unroll
  for (int mt = 0; mt < 4; ++mt)
#pragma unroll
    for (int nt = 0; nt < 4; ++nt) acc[mt][nt] = (f32x4){0.f, 0.f, 0.f, 0.f};

#pragma unroll 4
  for (int dk = 0; dk < 16; ++dk) {
    const int koff = dk * 32 + hi * 8;
    bf16x8 a[4], bfr[4];
#pragma unroll
    for (int mt = 0; mt < 4; ++mt)
      a[mt] = *reinterpret_cast<const bf16x8*>(&X[(size_t)(m0 + mt * 16 + lr) * DD + koff]);
#pragma unroll
    for (int nt = 0; nt < 4; ++nt)
      bfr[nt] = *reinterpret_cast<const bf16x8*>(&W[(size_t)(n0 + nt * 16 + lr) * DD + koff]);
#pragma unroll
    for (int mt = 0; mt < 4; ++mt)
#pragma unroll
      for (int nt = 0; nt < 4; ++nt) acc[mt][nt] = mfma16(a[mt], bfr[nt], acc[mt][nt]);
  }

#pragma unroll
  for (int nt = 0; nt < 4; ++nt) {
    const int col = n0 + nt * 16 + lr;
    const float bv = bias[col];
#pragma unroll
    for (int mt = 0; mt < 4; ++mt) {
#pragma unroll
      for (int r = 0; r < 4; ++r) {
        const int row = m0 + mt * 16 + hi * 4 + r;
        out[(size_t)row * DD + col] = f2bf(acc[mt][nt][r] + bv);
      }
    }
  }
}

// ---------------- V transpose per batch: VT[b][d][s] = V[b][s][d] ----------------
__global__ void vtrans_kernel(const unsigned short* __restrict__ V,
                              unsigned short* __restrict__ VT) {
  __shared__ unsigned short t[64][66];
  const int b = blockIdx.z;
  const int s0 = blockIdx.x * 64;
  const int d0 = blockIdx.y * 64;
  const int tid = threadIdx.x;
  const int c = tid & 63;
  const int rg = tid >> 6;
#pragma unroll
  for (int i = 0; i < 16; ++i) {
    const int row = rg * 16 + i;
    t[row][c] = V[((size_t)b * SS + s0 + row) * DD + d0 + c];
  }
  __syncthreads();
#pragma unroll
  for (int i = 0; i < 16; ++i) {
    const int row = rg * 16 + i;
    VT[((size_t)b * DD + d0 + row) * SS + s0 + c] = t[c][row];
  }
}

// ---------------- fused flash attention ----------------
// Each wave: 16 query rows, full D=512. Online softmax, masked keys.
__global__ __launch_bounds__(256, 2) void attn_kernel(
    const unsigned short* __restrict__ Q, const unsigned short* __restrict__ K,
    const unsigned short* __restrict__ VT, const int* __restrict__ mask,
    float* __restrict__ out) {
  __shared__ unsigned short pbuf[4][16][64];
  const int tid = threadIdx.x;
  const int w = tid >> 6;
  const int l = tid & 63;
  const int lr = l & 15;
  const int hi = l >> 4;
  const int b = blockIdx.y;
  const int q0 = blockIdx.x * 64 + w * 16;
  const float scale = 0.044194173824159216f;  // 1/sqrt(512)

  const unsigned short* __restrict__ Qb = Q + (size_t)b * SS * DD;
  const unsigned short* __restrict__ Kb = K + (size_t)b * SS * DD;
  const unsigned short* __restrict__ VTb = VT + (size_t)b * DD * SS;
  const int* __restrict__ maskb = mask + b * SS;

  f32x4 oacc[32];
#pragma unroll
  for (int i = 0; i < 32; ++i) oacc[i] = (f32x4){0.f, 0.f, 0.f, 0.f};
  float mrow[4], lrow[4];
#pragma unroll
  for (int r = 0; r < 4; ++r) {
    mrow[r] = -10000.0f;
    lrow[r] = 0.0f;
  }

  for (int kt = 0; kt < SS / 64; ++kt) {
    // ---- scores S[16 q][64 k] = Q @ K^T ----
    f32x4 sacc[4];
#pragma unroll
    for (int nt = 0; nt < 4; ++nt) sacc[nt] = (f32x4){0.f, 0.f, 0.f, 0.f};
#pragma unroll 4
    for (int dk = 0; dk < 16; ++dk) {
      const int koff = dk * 32 + hi * 8;
      bf16x8 aq = *reinterpret_cast<const bf16x8*>(&Qb[(size_t)(q0 + lr) * DD + koff]);
#pragma unroll
      for (int nt = 0; nt < 4; ++nt) {
        bf16x8 bk = *reinterpret_cast<const bf16x8*>(
            &Kb[(size_t)(kt * 64 + nt * 16 + lr) * DD + koff]);
        sacc[nt] = mfma16(aq, bk, sacc[nt]);
      }
    }
    // ---- scale + mask (mask indexes KEY position) ----
    int mk[4];
#pragma unroll
    for (int nt = 0; nt < 4; ++nt) mk[nt] = maskb[kt * 64 + nt * 16 + lr];
    float s[4][4];
#pragma unroll
    for (int nt = 0; nt < 4; ++nt)
#pragma unroll
      for (int r = 0; r < 4; ++r)
        s[nt][r] = mk[nt] ? sacc[nt][r] * scale : -10000.0f;

    // ---- online softmax (rows live in quads: row = hi*4 + r) ----
    float mnew[4], alpha[4];
#pragma unroll
    for (int r = 0; r < 4; ++r) {
      float mx = fmaxf(fmaxf(s[0][r], s[1][r]), fmaxf(s[2][r], s[3][r]));
#pragma unroll
      for (int off = 1; off < 16; off <<= 1) mx = fmaxf(mx, __shfl_xor(mx, off));
      mnew[r] = fmaxf(mrow[r], mx);
      alpha[r] = __expf(mrow[r] - mnew[r]);
      mrow[r] = mnew[r];
    }
    float rs[4] = {0.f, 0.f, 0.f, 0.f};
#pragma unroll
    for (int nt = 0; nt < 4; ++nt)
#pragma unroll
      for (int r = 0; r < 4; ++r) {
        float p = __expf(s[nt][r] - mnew[r]);
        s[nt][r] = p;
        rs[r] += p;
      }
#pragma unroll
    for (int r = 0; r < 4; ++r) {
      float t = rs[r];
#pragma unroll
      for (int off = 1; off < 16; off <<= 1) t += __shfl_xor(t, off);
      lrow[r] = lrow[r] * alpha[r] + t;
    }
    // ---- P: C-layout -> A-layout via per-wave LDS ----
#pragma unroll
    for (int nt = 0; nt < 4; ++nt)
#pragma unroll
      for (int r = 0; r < 4; ++r)
        pbuf[w][hi * 4 + r][nt * 16 + lr] = f2bf(s[nt][r]);
    bf16x8 pf0 = *reinterpret_cast<const bf16x8*>(&pbuf[w][lr][hi * 8]);
    bf16x8 pf1 = *reinterpret_cast<const bf16x8*>(&pbuf[w][lr][32 + hi * 8]);

    // ---- O = O*alpha + P @ V  (B-frags from VT rows) ----
#pragma unroll
    for (int nt2 = 0; nt2 < 32; ++nt2) {
      f32x4 c = oacc[nt2];
#pragma unroll
      for (int r = 0; r < 4; ++r) c[r] *= alpha[r];
      bf16x8 v0 = *reinterpret_cast<const bf16x8*>(
          &VTb[(size_t)(nt2 * 16 + lr) * SS + kt * 64 + hi * 8]);
      c = mfma16(pf0, v0, c);
      bf16x8 v1 = *reinterpret_cast<const bf16x8*>(
          &VTb[(size_t)(nt2 * 16 + lr) * SS + kt * 64 + 32 + hi * 8]);
      c = mfma16(pf1, v1, c);
      oacc[nt2] = c;
    }
  }

  // ---- epilogue: divide by l, store fp32 ----
  float inv[4];
#pragma unroll
  for (int r = 0; r < 4; ++r) inv[r] = 1.0f / lrow[r];
#pragma unroll
  for (int nt2 = 0; nt2 < 32; ++nt2)
#pragma unroll
    for (int r = 0; r < 4; ++r)
      out[((size_t)b * SS + q0 + hi * 4 + r) * DD + nt2 * 16 + lr] =
          oacc[nt2][r] * inv[r];
}

extern "C" void kernel_launch(void* const* d_in, const int* in_sizes, int n_in,
                              void* d_out, int out_size, void* d_ws, size_t ws_size,
                              hipStream_t stream) {
  const float* x = (const float*)d_in[0];
  const int* mask = (const int*)d_in[1];
  const float* Wq = (const float*)d_in[2];
  const float* bq = (const float*)d_in[3];
  const float* Wk = (const float*)d_in[4];
  const float* bk = (const float*)d_in[5];
  const float* Wv = (const float*)d_in[6];
  const float* bv = (const float*)d_in[7];
  float* out = (float*)d_out;

  char* ws = (char*)d_ws;
  const size_t MB = 1024 * 1024;
  unsigned short* Xb = (unsigned short*)(ws);
  unsigned short* Qb = (unsigned short*)(ws + 16 * MB);
  unsigned short* Kb = (unsigned short*)(ws + 32 * MB);
  unsigned short* Vb = (unsigned short*)(ws + 48 * MB);
  unsigned short* VTb = (unsigned short*)(ws + 64 * MB);
  unsigned short* Wqb = (unsigned short*)(ws + 80 * MB);
  unsigned short* Wkb = Wqb + 512 * 512;
  unsigned short* Wvb = Wkb + 512 * 512;

  // fp32 -> bf16
  cvt_bf16_kernel<<<8192, 256, 0, stream>>>(x, Xb, (MM * DD) / 4);
  cvt_bf16_kernel<<<256, 256, 0, stream>>>(Wq, Wqb, (DD * DD) / 4);
  cvt_bf16_kernel<<<256, 256, 0, stream>>>(Wk, Wkb, (DD * DD) / 4);
  cvt_bf16_kernel<<<256, 256, 0, stream>>>(Wv, Wvb, (DD * DD) / 4);

  // QKV projections
  dim3 gg(MM / 128, DD / 128);
  qkv_gemm_kernel<<<gg, 256, 0, stream>>>(Xb, Wqb, bq, Qb);
  qkv_gemm_kernel<<<gg, 256, 0, stream>>>(Xb, Wkb, bk, Kb);
  qkv_gemm_kernel<<<gg, 256, 0, stream>>>(Xb, Wvb, bv, Vb);

  // V transpose for PV B-operand
  vtrans_kernel<<<dim3(SS / 64, DD / 64, BB), 256, 0, stream>>>(Vb, VTb);

  // fused attention
  attn_kernel<<<dim3(SS / 64, BB), 256, 0, stream>>>(Qb, Kb, VTb, mask, out);
}

// Round 2
// 338.623 us; speedup vs baseline: 3.3742x; 3.3742x over previous
//
#include <hip/hip_runtime.h>
#include <cstddef>

#define BB 8
#define SS 2048
#define DD 512
#define MM (BB * SS)

typedef __attribute__((ext_vector_type(8))) short bf16x8;
typedef __attribute__((ext_vector_type(4))) float f32x4;
typedef __attribute__((ext_vector_type(4))) unsigned short u16x4;

__device__ __forceinline__ f32x4 mfma16(bf16x8 a, bf16x8 b, f32x4 c) {
  return __builtin_amdgcn_mfma_f32_16x16x32_bf16(a, b, c, 0, 0, 0);
}
__device__ __forceinline__ unsigned short f2bf(float f) {
  unsigned int u = __float_as_uint(f);
  u += 0x7fffu + ((u >> 16) & 1u);
  return (unsigned short)(u >> 16);
}
// async global->LDS: lds dest = base + lane*size (wave-uniform base!)
__device__ __forceinline__ void gld16(const void* g, void* l) {
  __builtin_amdgcn_global_load_lds((const __attribute__((address_space(1))) void*)g,
                                   (__attribute__((address_space(3))) void*)l, 16, 0, 0);
}
__device__ __forceinline__ void gld4(const void* g, void* l) {
  __builtin_amdgcn_global_load_lds((const __attribute__((address_space(1))) void*)g,
                                   (__attribute__((address_space(3))) void*)l, 4, 0, 0);
}

// ---------------- fp32 -> bf16 conversion ----------------
__global__ void cvt_bf16_kernel(const float* __restrict__ in,
                                unsigned short* __restrict__ out, int n4) {
  int i = blockIdx.x * blockDim.x + threadIdx.x;
  if (i >= n4) return;
  f32x4 v = reinterpret_cast<const f32x4*>(in)[i];
  u16x4 o;
  o[0] = f2bf(v[0]);
  o[1] = f2bf(v[1]);
  o[2] = f2bf(v[2]);
  o[3] = f2bf(v[3]);
  reinterpret_cast<u16x4*>(out)[i] = o;
}

// ---------------- fused QKV GEMM, m97-style LDS staging ----------------
// out[m][e] = sum_d X[m][d]*W[e][d] + b[e]; which W selected by blockIdx.y/4.
// LDS tiles 128 rows x 64 el, stored as [row][8 chunks of 16B], chunk slot
// XOR-swizzled with (row&7) so frag reads are bank-conflict-free while
// global_load_lds staging stays lane-contiguous in LDS.
__global__ __launch_bounds__(256, 2) void qkv_gemm_kernel(
    const unsigned short* __restrict__ X, const unsigned short* __restrict__ W0,
    const unsigned short* __restrict__ W1, const unsigned short* __restrict__ W2,
    const float* __restrict__ b0, const float* __restrict__ b1,
    const float* __restrict__ b2, unsigned short* __restrict__ O0,
    unsigned short* __restrict__ O1, unsigned short* __restrict__ O2) {
  __shared__ unsigned char a_lds[128 * 128];
  __shared__ unsigned char b_lds[128 * 128];
  const int tid = threadIdx.x;
  const int w = tid >> 6, l = tid & 63, lr = l & 15, hi = l >> 4;
  const int which = blockIdx.y >> 2;
  const unsigned short* W = which == 0 ? W0 : (which == 1 ? W1 : W2);
  const float* bias = which == 0 ? b0 : (which == 1 ? b1 : b2);
  unsigned short* out = which == 0 ? O0 : (which == 1 ? O1 : O2);
  const int m0 = blockIdx.x * 128;
  const int n0 = (blockIdx.y & 3) * 128;
  const int wm = (w >> 1) * 64, wn = (w & 1) * 64;
  const int srow = l >> 3, schunk = l & 7;
  const int gchunk = schunk ^ (srow & 7);  // global chunk this lane stages

  f32x4 acc[4][4];
#pragma unroll
  for (int mt = 0; mt < 4; ++mt)
#pragma unroll
    for (int nt = 0; nt < 4; ++nt) acc[mt][nt] = (f32x4){0.f, 0.f, 0.f, 0.f};

  const unsigned short* ga = X + (size_t)(m0 + w * 32 + srow) * DD + gchunk * 8;
  const unsigned short* gb = W + (size_t)(n0 + w * 32 + srow) * DD + gchunk * 8;

  for (int k0 = 0; k0 < DD; k0 += 64) {
#pragma unroll
    for (int ii = 0; ii < 4; ++ii) {
      gld16(ga + (size_t)ii * 8 * DD + k0, &a_lds[(w * 4 + ii) * 1024]);
      gld16(gb + (size_t)ii * 8 * DD + k0, &b_lds[(w * 4 + ii) * 1024]);
    }
    __syncthreads();
#pragma unroll
    for (int dkl = 0; dkl < 2; ++dkl) {
      const int gc = dkl * 4 + hi;
      bf16x8 af[4], bfr[4];
#pragma unroll
      for (int mt = 0; mt < 4; ++mt) {
        const int row = wm + mt * 16 + lr;
        af[mt] = *reinterpret_cast<const bf16x8*>(
            &a_lds[row * 128 + ((gc ^ (row & 7)) * 16)]);
      }
#pragma unroll
      for (int nt = 0; nt < 4; ++nt) {
        const int row = wn + nt * 16 + lr;
        bfr[nt] = *reinterpret_cast<const bf16x8*>(
            &b_lds[row * 128 + ((gc ^ (row & 7)) * 16)]);
      }
#pragma unroll
      for (int mt = 0; mt < 4; ++mt)
#pragma unroll
        for (int nt = 0; nt < 4; ++nt)
          acc[mt][nt] = mfma16(af[mt], bfr[nt], acc[mt][nt]);
    }
    __syncthreads();
  }

#pragma unroll
  for (int nt = 0; nt < 4; ++nt) {
    const int col = n0 + wn + nt * 16 + lr;
    const float bv = bias[col];
#pragma unroll
    for (int mt = 0; mt < 4; ++mt)
#pragma unroll
      for (int r = 0; r < 4; ++r) {
        const int row = m0 + wm + mt * 16 + hi * 4 + r;
        out[(size_t)row * DD + col] = f2bf(acc[mt][nt][r] + bv);
      }
  }
}

// ---------------- V tiled-transpose ----------------
// VT2[b][kt][cc][d][jj] = V[b][kt*64 + cc*8 + jj][d]  (jj in 0..7, cc in 0..7)
// This is exactly the LDS layout attn stages per 64-key tile, so staging
// reads are fully contiguous 1KB global_load_lds.
__global__ void vtrans_kernel(const unsigned short* __restrict__ V,
                              unsigned short* __restrict__ VT2) {
  __shared__ unsigned short t[64][72];
  const int b = blockIdx.z;
  const int kt = blockIdx.x;
  const int d0 = blockIdx.y * 64;
  const int tid = threadIdx.x;
  const int c = tid & 63, rg = tid >> 6;
#pragma unroll
  for (int i = 0; i < 16; ++i) {
    const int row = rg * 16 + i;
    t[row][c] = V[((size_t)b * SS + kt * 64 + row) * DD + d0 + c];
  }
  __syncthreads();
#pragma unroll
  for (int i = 0; i < 16; ++i) {
    const int idx = i * 256 + tid;
    const int jj = idx & 7;
    const int dl = (idx >> 3) & 63;
    const int cc = idx >> 9;
    VT2[(((size_t)(b * 32 + kt) * 8 + cc) * 512 + d0 + dl) * 8 + jj] =
        t[cc * 8 + jj][dl];
  }
}

// ---------------- fused flash attention, LDS-staged K/V tiles ----------------
__global__ __launch_bounds__(256, 1) void attn_kernel(
    const unsigned short* __restrict__ Q, const unsigned short* __restrict__ K,
    const unsigned short* __restrict__ VT2, const int* __restrict__ mask,
    float* __restrict__ out) {
  __shared__ unsigned char k_lds[64 * 1040];      // 64 key rows, 1040B stride (pad)
  __shared__ unsigned char vt_lds[8 * 512 * 16];  // [chunk][d][8 keys]
  __shared__ unsigned short pbuf[4][16][64];
  __shared__ int mask_lds[64];
  const int tid = threadIdx.x;
  const int w = tid >> 6, l = tid & 63, lr = l & 15, hi = l >> 4;
  const int b = blockIdx.y;
  const int q0 = blockIdx.x * 64 + w * 16;
  const float scale = 0.044194173824159216f;  // 1/sqrt(512)

  const unsigned short* __restrict__ Qb = Q + (size_t)b * SS * DD;
  const unsigned short* __restrict__ Kb = K + (size_t)b * SS * DD;
  const unsigned short* __restrict__ Vb = VT2 + (size_t)b * SS * DD;
  const int* __restrict__ maskb = mask + b * SS;

  // Q fragments held in registers for the whole kernel (16 KB/wave -> 64 VGPR)
  bf16x8 qf[16];
#pragma unroll
  for (int dk = 0; dk < 16; ++dk)
    qf[dk] = *reinterpret_cast<const bf16x8*>(
        &Qb[(size_t)(q0 + lr) * DD + dk * 32 + hi * 8]);

  f32x4 oacc[32];
#pragma unroll
  for (int i = 0; i < 32; ++i) oacc[i] = (f32x4){0.f, 0.f, 0.f, 0.f};
  float mrow[4], lrow[4];
#pragma unroll
  for (int r = 0; r < 4; ++r) {
    mrow[r] = -10000.0f;
    lrow[r] = 0.0f;
  }

  const unsigned short* kg = Kb + (size_t)(w * 16) * DD + l * 8;

  for (int kt = 0; kt < 32; ++kt) {
    // ---- stage K tile: wave w stages key rows w*16 .. w*16+15 (1KB each) ----
#pragma unroll
    for (int r = 0; r < 16; ++r)
      gld16(kg + (size_t)(kt * 64 + r) * DD, &k_lds[(w * 16 + r) * 1040]);
    // ---- stage V tile: 64 instrs of 1KB, wave w does chunks 2w..2w+1 ----
#pragma unroll
    for (int ii = 0; ii < 16; ++ii) {
      const int c = w * 2 + (ii >> 3), g = ii & 7;
      gld16(Vb + ((size_t)(kt * 8 + c) * 512 + g * 64 + l) * 8,
            &vt_lds[(c * 512 + g * 64) * 16]);
    }
    if (w == 0) gld4(maskb + kt * 64 + l, mask_lds);
    __syncthreads();

    int mk[4];
#pragma unroll
    for (int nt = 0; nt < 4; ++nt) mk[nt] = mask_lds[nt * 16 + lr];

    // ---- S = Q @ K^T ----
    f32x4 sacc[4];
#pragma unroll
    for (int nt = 0; nt < 4; ++nt) sacc[nt] = (f32x4){0.f, 0.f, 0.f, 0.f};
#pragma unroll
    for (int dk = 0; dk < 16; ++dk) {
#pragma unroll
      for (int nt = 0; nt < 4; ++nt) {
        bf16x8 bk = *reinterpret_cast<const bf16x8*>(
            &k_lds[(nt * 16 + lr) * 1040 + dk * 64 + hi * 16]);
        sacc[nt] = mfma16(qf[dk], bk, sacc[nt]);
      }
    }

    float s[4][4];
#pragma unroll
    for (int nt = 0; nt < 4; ++nt)
#pragma unroll
      for (int r = 0; r < 4; ++r)
        s[nt][r] = mk[nt] ? sacc[nt][r] * scale : -10000.0f;

    // ---- online softmax (row = hi*4 + r within quad) ----
    float mnew[4], alpha[4];
#pragma unroll
    for (int r = 0; r < 4; ++r) {
      float mx = fmaxf(fmaxf(s[0][r], s[1][r]), fmaxf(s[2][r], s[3][r]));
#pragma unroll
      for (int off = 1; off < 16; off <<= 1) mx = fmaxf(mx, __shfl_xor(mx, off));
      mnew[r] = fmaxf(mrow[r], mx);
      alpha[r] = __expf(mrow[r] - mnew[r]);
      mrow[r] = mnew[r];
    }
    float rs[4] = {0.f, 0.f, 0.f, 0.f};
#pragma unroll
    for (int nt = 0; nt < 4; ++nt)
#pragma unroll
      for (int r = 0; r < 4; ++r) {
        float p = __expf(s[nt][r] - mnew[r]);
        s[nt][r] = p;
        rs[r] += p;
      }
#pragma unroll
    for (int r = 0; r < 4; ++r) {
      float t = rs[r];
#pragma unroll
      for (int off = 1; off < 16; off <<= 1) t += __shfl_xor(t, off);
      lrow[r] = lrow[r] * alpha[r] + t;
    }

    // ---- P: C-layout -> A-layout via per-wave LDS (verified R1) ----
#pragma unroll
    for (int nt = 0; nt < 4; ++nt)
#pragma unroll
      for (int r = 0; r < 4; ++r)
        pbuf[w][hi * 4 + r][nt * 16 + lr] = f2bf(s[nt][r]);
    bf16x8 pf0 = *reinterpret_cast<const bf16x8*>(&pbuf[w][lr][hi * 8]);
    bf16x8 pf1 = *reinterpret_cast<const bf16x8*>(&pbuf[w][lr][32 + hi * 8]);

    // ---- O = O*alpha + P @ V ----
#pragma unroll
    for (int nt2 = 0; nt2 < 32; ++nt2) {
      f32x4 c = oacc[nt2];
#pragma unroll
      for (int r = 0; r < 4; ++r) c[r] *= alpha[r];
      bf16x8 v0 = *reinterpret_cast<const bf16x8*>(
          &vt_lds[(hi * 512 + nt2 * 16 + lr) * 16]);
      c = mfma16(pf0, v0, c);
      bf16x8 v1 = *reinterpret_cast<const bf16x8*>(
          &vt_lds[((4 + hi) * 512 + nt2 * 16 + lr) * 16]);
      c = mfma16(pf1, v1, c);
      oacc[nt2] = c;
    }
    __syncthreads();
  }

  float inv[4];
#pragma unroll
  for (int r = 0; r < 4; ++r) inv[r] = 1.0f / lrow[r];
#pragma unroll
  for (int nt2 = 0; nt2 < 32; ++nt2)
#pragma unroll
    for (int r = 0; r < 4; ++r)
      out[((size_t)b * SS + q0 + hi * 4 + r) * DD + nt2 * 16 + lr] =
          oacc[nt2][r] * inv[r];
}

extern "C" void kernel_launch(void* const* d_in, const int* in_sizes, int n_in,
                              void* d_out, int out_size, void* d_ws, size_t ws_size,
                              hipStream_t stream) {
  const float* x = (const float*)d_in[0];
  const int* mask = (const int*)d_in[1];
  const float* Wq = (const float*)d_in[2];
  const float* bq = (const float*)d_in[3];
  const float* Wk = (const float*)d_in[4];
  const float* bk = (const float*)d_in[5];
  const float* Wv = (const float*)d_in[6];
  const float* bv = (const float*)d_in[7];
  float* out = (float*)d_out;

  char* ws = (char*)d_ws;
  const size_t MB = 1024 * 1024;
  unsigned short* Xb = (unsigned short*)(ws);
  unsigned short* Qb = (unsigned short*)(ws + 16 * MB);
  unsigned short* Kb = (unsigned short*)(ws + 32 * MB);
  unsigned short* Vb = (unsigned short*)(ws + 48 * MB);
  unsigned short* VT2b = (unsigned short*)(ws + 64 * MB);
  unsigned short* Wqb = (unsigned short*)(ws + 80 * MB);
  unsigned short* Wkb = Wqb + 512 * 512;
  unsigned short* Wvb = Wkb + 512 * 512;

  cvt_bf16_kernel<<<8192, 256, 0, stream>>>(x, Xb, (MM * DD) / 4);
  cvt_bf16_kernel<<<256, 256, 0, stream>>>(Wq, Wqb, (DD * DD) / 4);
  cvt_bf16_kernel<<<256, 256, 0, stream>>>(Wk, Wkb, (DD * DD) / 4);
  cvt_bf16_kernel<<<256, 256, 0, stream>>>(Wv, Wvb, (DD * DD) / 4);

  qkv_gemm_kernel<<<dim3(MM / 128, 12), 256, 0, stream>>>(
      Xb, Wqb, Wkb, Wvb, bq, bk, bv, Qb, Kb, Vb);

  vtrans_kernel<<<dim3(SS / 64, DD / 64, BB), 256, 0, stream>>>(Vb, VT2b);

  attn_kernel<<<dim3(SS / 64, BB), 256, 0, stream>>>(Qb, Kb, VT2b, mask, out);
}

// Round 3
// 275.983 us; speedup vs baseline: 4.1401x; 1.2270x over previous
//
#include <hip/hip_runtime.h>
#include <cstddef>

#define BB 8
#define SS 2048
#define DD 512
#define MM (BB * SS)

typedef __attribute__((ext_vector_type(8))) short bf16x8;
typedef __attribute__((ext_vector_type(4))) float f32x4;
typedef __attribute__((ext_vector_type(4))) unsigned short u16x4;

__device__ __forceinline__ f32x4 mfma16(bf16x8 a, bf16x8 b, f32x4 c) {
  return __builtin_amdgcn_mfma_f32_16x16x32_bf16(a, b, c, 0, 0, 0);
}
__device__ __forceinline__ unsigned short f2bf(float f) {
  unsigned int u = __float_as_uint(f);
  u += 0x7fffu + ((u >> 16) & 1u);
  return (unsigned short)(u >> 16);
}
__device__ __forceinline__ void gld16(const void* g, void* l) {
  __builtin_amdgcn_global_load_lds((const __attribute__((address_space(1))) void*)g,
                                   (__attribute__((address_space(3))) void*)l, 16, 0, 0);
}

// ---------------- fp32 -> bf16 ----------------
__global__ void cvt_bf16_kernel(const float* __restrict__ in,
                                unsigned short* __restrict__ out, int n4) {
  int i = blockIdx.x * blockDim.x + threadIdx.x;
  if (i >= n4) return;
  f32x4 v = reinterpret_cast<const f32x4*>(in)[i];
  u16x4 o;
  o[0] = f2bf(v[0]);
  o[1] = f2bf(v[1]);
  o[2] = f2bf(v[2]);
  o[3] = f2bf(v[3]);
  reinterpret_cast<u16x4*>(out)[i] = o;
}

// ---------------- per-batch mask scan: active-key index list ----------------
__global__ void mask_scan_kernel(const int* __restrict__ mask, int* __restrict__ idx,
                                 int* __restrict__ nbArr) {
  __shared__ int part[256];
  const int b = blockIdx.x;
  const int t = threadIdx.x;
  int m[8], c = 0;
#pragma unroll
  for (int e = 0; e < 8; ++e) {
    m[e] = mask[b * SS + t * 8 + e];
    c += (m[e] != 0);
  }
  int v = c;
  part[t] = v;
  __syncthreads();
  for (int off = 1; off < 256; off <<= 1) {
    int u = (t >= off) ? part[t - off] : 0;
    __syncthreads();
    v += u;
    part[t] = v;
    __syncthreads();
  }
  int base = v - c;
#pragma unroll
  for (int e = 0; e < 8; ++e)
    if (m[e]) idx[b * SS + base++] = t * 8 + e;
  if (t == 255) nbArr[b] = part[255];
}

// ---------------- gather compacted K rows ----------------
__global__ void gatherk_kernel(const unsigned short* __restrict__ K,
                               const int* __restrict__ idx, const int* __restrict__ nbArr,
                               unsigned short* __restrict__ Kc) {
  const int b = blockIdx.y;
  const int j = blockIdx.x * 4 + (threadIdx.x >> 6);
  const int l = threadIdx.x & 63;
  if (j >= nbArr[b]) return;
  const int src = idx[b * SS + j];
  bf16x8 v = *reinterpret_cast<const bf16x8*>(&K[((size_t)b * SS + src) * DD + l * 8]);
  *reinterpret_cast<bf16x8*>(&Kc[((size_t)b * SS + j) * DD + l * 8]) = v;
}

// ---------------- fused QKV GEMM, 256x128 tiles ----------------
__global__ __launch_bounds__(256, 2) void qkv_gemm_kernel(
    const unsigned short* __restrict__ X, const unsigned short* __restrict__ W0,
    const unsigned short* __restrict__ W1, const unsigned short* __restrict__ W2,
    const float* __restrict__ b0, const float* __restrict__ b1,
    const float* __restrict__ b2, unsigned short* __restrict__ O0,
    unsigned short* __restrict__ O1, unsigned short* __restrict__ O2) {
  __shared__ unsigned char a_lds[256 * 128];
  __shared__ unsigned char b_lds[128 * 128];
  const int tid = threadIdx.x;
  const int w = tid >> 6, l = tid & 63, lr = l & 15, hi = l >> 4;
  const int which = blockIdx.y >> 2;
  const unsigned short* W = which == 0 ? W0 : (which == 1 ? W1 : W2);
  const float* bias = which == 0 ? b0 : (which == 1 ? b1 : b2);
  unsigned short* out = which == 0 ? O0 : (which == 1 ? O1 : O2);
  const int m0 = blockIdx.x * 256;
  const int n0 = (blockIdx.y & 3) * 128;
  const int srow = l >> 3, gchunk = (l & 7) ^ (srow & 7);

  f32x4 acc[4][8];
#pragma unroll
  for (int mt = 0; mt < 4; ++mt)
#pragma unroll
    for (int nt = 0; nt < 8; ++nt) acc[mt][nt] = (f32x4){0.f, 0.f, 0.f, 0.f};

  const unsigned short* ga = X + (size_t)(m0 + w * 64 + srow) * DD + gchunk * 8;
  const unsigned short* gb = W + (size_t)(n0 + w * 32 + srow) * DD + gchunk * 8;

  for (int k0 = 0; k0 < DD; k0 += 64) {
#pragma unroll
    for (int ii = 0; ii < 8; ++ii)
      gld16(ga + (size_t)(ii * 8) * DD + k0, &a_lds[(w * 8 + ii) * 1024]);
#pragma unroll
    for (int ii = 0; ii < 4; ++ii)
      gld16(gb + (size_t)(ii * 8) * DD + k0, &b_lds[(w * 4 + ii) * 1024]);
    __syncthreads();
#pragma unroll
    for (int dkl = 0; dkl < 2; ++dkl) {
      const int gc = dkl * 4 + hi;
      bf16x8 af[4], bfr[8];
#pragma unroll
      for (int mt = 0; mt < 4; ++mt) {
        const int row = w * 64 + mt * 16 + lr;
        af[mt] = *reinterpret_cast<const bf16x8*>(
            &a_lds[row * 128 + ((gc ^ (row & 7)) * 16)]);
      }
#pragma unroll
      for (int nt = 0; nt < 8; ++nt) {
        const int row = nt * 16 + lr;
        bfr[nt] = *reinterpret_cast<const bf16x8*>(
            &b_lds[row * 128 + ((gc ^ (row & 7)) * 16)]);
      }
#pragma unroll
      for (int mt = 0; mt < 4; ++mt)
#pragma unroll
        for (int nt = 0; nt < 8; ++nt)
          acc[mt][nt] = mfma16(af[mt], bfr[nt], acc[mt][nt]);
    }
    __syncthreads();
  }

#pragma unroll
  for (int nt = 0; nt < 8; ++nt) {
    const int col = n0 + nt * 16 + lr;
    const float bv = bias[col];
#pragma unroll
    for (int mt = 0; mt < 4; ++mt)
#pragma unroll
      for (int r = 0; r < 4; ++r) {
        const int row = m0 + w * 64 + mt * 16 + hi * 4 + r;
        out[(size_t)row * DD + col] = f2bf(acc[mt][nt][r] + bv);
      }
  }
}

// ---------------- V gather+tiled-transpose ----------------
// VT2[b][g][d][jj] = Vc[b][g*8+jj][d], g = key/8 (compacted keys)
__global__ void vtrans_kernel(const unsigned short* __restrict__ V,
                              const int* __restrict__ idx, const int* __restrict__ nbArr,
                              unsigned short* __restrict__ VT2) {
  __shared__ unsigned short t[64][72];
  const int b = blockIdx.z;
  const int kt = blockIdx.x;
  const int d0 = blockIdx.y * 64;
  const int tid = threadIdx.x;
  const int c = tid & 63, rg = tid >> 6;
  const int nb = nbArr[b];
#pragma unroll
  for (int i = 0; i < 16; ++i) {
    const int row = rg * 16 + i;
    const int s = kt * 64 + row;
    const int src = s < nb ? idx[b * SS + s] : 0;
    t[row][c] = V[((size_t)b * SS + src) * DD + d0 + c];
  }
  __syncthreads();
#pragma unroll
  for (int i = 0; i < 16; ++i) {
    const int ix = i * 256 + tid;
    const int jj = ix & 7;
    const int dl = (ix >> 3) & 63;
    const int cc = ix >> 9;
    VT2[(((size_t)(b * 32 + kt) * 8 + cc) * 512 + d0 + dl) * 8 + jj] =
        t[cc * 8 + jj][dl];
  }
}

// ---------------- fused flash attention: compacted keys, dbuf staging ----------------
__global__ __launch_bounds__(256, 1) void attn_kernel(
    const unsigned short* __restrict__ Q, const unsigned short* __restrict__ Kc,
    const unsigned short* __restrict__ VT2, const int* __restrict__ nbArr,
    float* __restrict__ out) {
  __shared__ unsigned char k_lds[2][32 * 1040];
  __shared__ unsigned char vt_lds[2][4 * 512 * 16];
  __shared__ unsigned short pbuf[4][16][32];
  const int tid = threadIdx.x;
  const int w = tid >> 6, l = tid & 63, lr = l & 15, hi = l >> 4;
  const int b = blockIdx.y;
  const int q0 = blockIdx.x * 64 + w * 16;
  const float scale = 0.044194173824159216f;  // 1/sqrt(512)

  const int nb = nbArr[b];
  const int ntile = (nb + 31) >> 5;

  const unsigned short* __restrict__ Qb = Q + (size_t)b * SS * DD;
  const unsigned short* __restrict__ Kb = Kc + (size_t)b * SS * DD;
  const unsigned short* __restrict__ Vb = VT2 + (size_t)b * SS * DD;

  bf16x8 qf[16];
#pragma unroll
  for (int dk = 0; dk < 16; ++dk)
    qf[dk] = *reinterpret_cast<const bf16x8*>(
        &Qb[(size_t)(q0 + lr) * DD + dk * 32 + hi * 8]);

  f32x4 oacc[32];
#pragma unroll
  for (int i = 0; i < 32; ++i) oacc[i] = (f32x4){0.f, 0.f, 0.f, 0.f};
  float mrow[4], lrow[4];
#pragma unroll
  for (int r = 0; r < 4; ++r) {
    mrow[r] = -10000.0f;
    lrow[r] = 0.0f;
  }

  const unsigned short* kg = Kb + (size_t)(w * 8) * DD + l * 8;
  const unsigned short* vg = Vb + (size_t)(w * 512) * 8 + l * 8;

  auto stage = [&](int kt, int bufi) {
#pragma unroll
    for (int r = 0; r < 8; ++r)
      gld16(kg + (size_t)(kt * 32 + r) * DD, &k_lds[bufi][(w * 8 + r) * 1040]);
#pragma unroll
    for (int g = 0; g < 8; ++g)
      gld16(vg + ((size_t)kt * 4 * 512 + g * 64) * 8,
            &vt_lds[bufi][(w * 512 + g * 64) * 16]);
  };

  if (ntile > 0) stage(0, 0);

  for (int kt = 0; kt < ntile; ++kt) {
    __syncthreads();
    if (kt + 1 < ntile) stage(kt + 1, (kt + 1) & 1);
    const int bufi = kt & 1;

    // ---- S = Q @ K^T (32 keys) ----
    f32x4 sacc[2];
#pragma unroll
    for (int nt = 0; nt < 2; ++nt) sacc[nt] = (f32x4){0.f, 0.f, 0.f, 0.f};
#pragma unroll
    for (int dk = 0; dk < 16; ++dk) {
#pragma unroll
      for (int nt = 0; nt < 2; ++nt) {
        bf16x8 bk = *reinterpret_cast<const bf16x8*>(
            &k_lds[bufi][(nt * 16 + lr) * 1040 + dk * 64 + hi * 16]);
        sacc[nt] = mfma16(qf[dk], bk, sacc[nt]);
      }
    }

    float s[2][4];
#pragma unroll
    for (int nt = 0; nt < 2; ++nt) {
      const int j = kt * 32 + nt * 16 + lr;
      const bool ok = j < nb;
#pragma unroll
      for (int r = 0; r < 4; ++r)
        s[nt][r] = ok ? sacc[nt][r] * scale : -10000.0f;
    }

    // ---- online softmax ----
    float mnew[4], alpha[4];
#pragma unroll
    for (int r = 0; r < 4; ++r) {
      float mx = fmaxf(s[0][r], s[1][r]);
#pragma unroll
      for (int off = 1; off < 16; off <<= 1) mx = fmaxf(mx, __shfl_xor(mx, off));
      mnew[r] = fmaxf(mrow[r], mx);
      alpha[r] = __expf(mrow[r] - mnew[r]);
      mrow[r] = mnew[r];
    }
    float rs[4] = {0.f, 0.f, 0.f, 0.f};
#pragma unroll
    for (int nt = 0; nt < 2; ++nt)
#pragma unroll
      for (int r = 0; r < 4; ++r) {
        float p = __expf(s[nt][r] - mnew[r]);
        s[nt][r] = p;
        rs[r] += p;
      }
#pragma unroll
    for (int r = 0; r < 4; ++r) {
      float t = rs[r];
#pragma unroll
      for (int off = 1; off < 16; off <<= 1) t += __shfl_xor(t, off);
      lrow[r] = lrow[r] * alpha[r] + t;
    }

    // ---- P relayout C->A via per-wave LDS ----
#pragma unroll
    for (int nt = 0; nt < 2; ++nt)
#pragma unroll
      for (int r = 0; r < 4; ++r)
        pbuf[w][hi * 4 + r][nt * 16 + lr] = f2bf(s[nt][r]);
    bf16x8 pf = *reinterpret_cast<const bf16x8*>(&pbuf[w][lr][hi * 8]);

    // ---- O = O*alpha + P @ V ----
#pragma unroll
    for (int nt2 = 0; nt2 < 32; ++nt2) {
      f32x4 c = oacc[nt2];
#pragma unroll
      for (int r = 0; r < 4; ++r) c[r] *= alpha[r];
      bf16x8 v0 = *reinterpret_cast<const bf16x8*>(
          &vt_lds[bufi][(hi * 512 + nt2 * 16 + lr) * 16]);
      oacc[nt2] = mfma16(pf, v0, c);
    }
  }

  float inv[4];
#pragma unroll
  for (int r = 0; r < 4; ++r) inv[r] = 1.0f / lrow[r];
#pragma unroll
  for (int nt2 = 0; nt2 < 32; ++nt2)
#pragma unroll
    for (int r = 0; r < 4; ++r)
      out[((size_t)b * SS + q0 + hi * 4 + r) * DD + nt2 * 16 + lr] =
          oacc[nt2][r] * inv[r];
}

extern "C" void kernel_launch(void* const* d_in, const int* in_sizes, int n_in,
                              void* d_out, int out_size, void* d_ws, size_t ws_size,
                              hipStream_t stream) {
  const float* x = (const float*)d_in[0];
  const int* mask = (const int*)d_in[1];
  const float* Wq = (const float*)d_in[2];
  const float* bq = (const float*)d_in[3];
  const float* Wk = (const float*)d_in[4];
  const float* bk = (const float*)d_in[5];
  const float* Wv = (const float*)d_in[6];
  const float* bv = (const float*)d_in[7];
  float* out = (float*)d_out;

  char* ws = (char*)d_ws;
  const size_t MB = 1024 * 1024;
  unsigned short* Xb = (unsigned short*)(ws);          // also reused as Kc after qkv
  unsigned short* Qb = (unsigned short*)(ws + 16 * MB);
  unsigned short* Kb = (unsigned short*)(ws + 32 * MB);
  unsigned short* Vb = (unsigned short*)(ws + 48 * MB);
  unsigned short* VT2b = (unsigned short*)(ws + 64 * MB);
  unsigned short* Wqb = (unsigned short*)(ws + 80 * MB);
  unsigned short* Wkb = Wqb + 512 * 512;
  unsigned short* Wvb = Wkb + 512 * 512;
  int* idx = (int*)(ws + 80 * MB + 2 * MB);            // 64 KB
  int* nbArr = (int*)(ws + 80 * MB + 2 * MB + 65536);  // 32 B
  unsigned short* Kc = Xb;                             // alias: safe after qkv

  cvt_bf16_kernel<<<8192, 256, 0, stream>>>(x, Xb, (MM * DD) / 4);
  cvt_bf16_kernel<<<256, 256, 0, stream>>>(Wq, Wqb, (DD * DD) / 4);
  cvt_bf16_kernel<<<256, 256, 0, stream>>>(Wk, Wkb, (DD * DD) / 4);
  cvt_bf16_kernel<<<256, 256, 0, stream>>>(Wv, Wvb, (DD * DD) / 4);

  mask_scan_kernel<<<BB, 256, 0, stream>>>(mask, idx, nbArr);

  qkv_gemm_kernel<<<dim3(MM / 256, 12), 256, 0, stream>>>(
      Xb, Wqb, Wkb, Wvb, bq, bk, bv, Qb, Kb, Vb);

  gatherk_kernel<<<dim3(SS / 4, BB), 256, 0, stream>>>(Kb, idx, nbArr, Kc);
  vtrans_kernel<<<dim3(SS / 64, DD / 64, BB), 256, 0, stream>>>(Vb, idx, nbArr, VT2b);

  attn_kernel<<<dim3(SS / 64, BB), 256, 0, stream>>>(Qb, Kc, VT2b, nbArr, out);
}

// Round 5
// 252.107 us; speedup vs baseline: 4.5321x; 1.0947x over previous
//
#include <hip/hip_runtime.h>
#include <cstddef>

#define BB 8
#define SS 2048
#define DD 512
#define MM (BB * SS)

typedef __attribute__((ext_vector_type(8))) short bf16x8;
typedef __attribute__((ext_vector_type(4))) float f32x4;
typedef __attribute__((ext_vector_type(4))) unsigned short u16x4;

__device__ __forceinline__ f32x4 mfma16(bf16x8 a, bf16x8 b, f32x4 c) {
  return __builtin_amdgcn_mfma_f32_16x16x32_bf16(a, b, c, 0, 0, 0);
}
__device__ __forceinline__ unsigned short f2bf(float f) {
  unsigned int u = __float_as_uint(f);
  u += 0x7fffu + ((u >> 16) & 1u);
  return (unsigned short)(u >> 16);
}
__device__ __forceinline__ void gld16(const void* g, void* l) {
  __builtin_amdgcn_global_load_lds((const __attribute__((address_space(1))) void*)g,
                                   (__attribute__((address_space(3))) void*)l, 16, 0, 0);
}

// ---------------- fp32 -> bf16 ----------------
__global__ void cvt_bf16_kernel(const float* __restrict__ in,
                                unsigned short* __restrict__ out, int n4) {
  int i = blockIdx.x * blockDim.x + threadIdx.x;
  if (i >= n4) return;
  f32x4 v = reinterpret_cast<const f32x4*>(in)[i];
  u16x4 o;
  o[0] = f2bf(v[0]);
  o[1] = f2bf(v[1]);
  o[2] = f2bf(v[2]);
  o[3] = f2bf(v[3]);
  reinterpret_cast<u16x4*>(out)[i] = o;
}
// 3 weight matrices in one launch
__global__ void cvt_w3_kernel(const float* __restrict__ s0, const float* __restrict__ s1,
                              const float* __restrict__ s2, unsigned short* __restrict__ d0,
                              unsigned short* __restrict__ d1, unsigned short* __restrict__ d2) {
  const float* s = blockIdx.y == 0 ? s0 : (blockIdx.y == 1 ? s1 : s2);
  unsigned short* d = blockIdx.y == 0 ? d0 : (blockIdx.y == 1 ? d1 : d2);
  int i = blockIdx.x * blockDim.x + threadIdx.x;
  f32x4 v = reinterpret_cast<const f32x4*>(s)[i];
  u16x4 o;
  o[0] = f2bf(v[0]);
  o[1] = f2bf(v[1]);
  o[2] = f2bf(v[2]);
  o[3] = f2bf(v[3]);
  reinterpret_cast<u16x4*>(d)[i] = o;
}

// ---------------- per-batch mask scan: active-key index list (tail zeroed) ----------------
__global__ void mask_scan_kernel(const int* __restrict__ mask, int* __restrict__ idx,
                                 int* __restrict__ nbArr) {
  __shared__ int part[256];
  const int b = blockIdx.x;
  const int t = threadIdx.x;
  int m[8], c = 0;
#pragma unroll
  for (int e = 0; e < 8; ++e) {
    m[e] = mask[b * SS + t * 8 + e];
    c += (m[e] != 0);
  }
  int v = c;
  part[t] = v;
  __syncthreads();
  for (int off = 1; off < 256; off <<= 1) {
    int u = (t >= off) ? part[t - off] : 0;
    __syncthreads();
    v += u;
    part[t] = v;
    __syncthreads();
  }
  int base = v - c;
#pragma unroll
  for (int e = 0; e < 8; ++e)
    if (m[e]) idx[b * SS + base++] = t * 8 + e;
  const int nb = part[255];
  if (t == 255) nbArr[b] = nb;
  for (int j = nb + t; j < SS; j += 256) idx[b * SS + j] = 0;
}

// ---------------- fused QKV GEMM (R2-verified 128x128 shape) ----------------
__global__ __launch_bounds__(256, 2) void qkv_gemm_kernel(
    const unsigned short* __restrict__ X, const unsigned short* __restrict__ W0,
    const unsigned short* __restrict__ W1, const unsigned short* __restrict__ W2,
    const float* __restrict__ b0, const float* __restrict__ b1,
    const float* __restrict__ b2, unsigned short* __restrict__ O0,
    unsigned short* __restrict__ O1, unsigned short* __restrict__ O2) {
  __shared__ unsigned char a_lds[128 * 128];
  __shared__ unsigned char b_lds[128 * 128];
  const int tid = threadIdx.x;
  const int w = tid >> 6, l = tid & 63, lr = l & 15, hi = l >> 4;
  const int which = blockIdx.y >> 2;
  const unsigned short* W = which == 0 ? W0 : (which == 1 ? W1 : W2);
  const float* bias = which == 0 ? b0 : (which == 1 ? b1 : b2);
  unsigned short* out = which == 0 ? O0 : (which == 1 ? O1 : O2);
  const int m0 = blockIdx.x * 128;
  const int n0 = (blockIdx.y & 3) * 128;
  const int wm = (w >> 1) * 64, wn = (w & 1) * 64;
  const int srow = l >> 3, gchunk = (l & 7) ^ (srow & 7);

  f32x4 acc[4][4];
#pragma unroll
  for (int mt = 0; mt < 4; ++mt)
#pragma unroll
    for (int nt = 0; nt < 4; ++nt) acc[mt][nt] = (f32x4){0.f, 0.f, 0.f, 0.f};

  const unsigned short* ga = X + (size_t)(m0 + w * 32 + srow) * DD + gchunk * 8;
  const unsigned short* gb = W + (size_t)(n0 + w * 32 + srow) * DD + gchunk * 8;

  for (int k0 = 0; k0 < DD; k0 += 64) {
#pragma unroll
    for (int ii = 0; ii < 4; ++ii) {
      gld16(ga + (size_t)ii * 8 * DD + k0, &a_lds[(w * 4 + ii) * 1024]);
      gld16(gb + (size_t)ii * 8 * DD + k0, &b_lds[(w * 4 + ii) * 1024]);
    }
    __syncthreads();
#pragma unroll
    for (int dkl = 0; dkl < 2; ++dkl) {
      const int gc = dkl * 4 + hi;
      bf16x8 af[4], bfr[4];
#pragma unroll
      for (int mt = 0; mt < 4; ++mt) {
        const int row = wm + mt * 16 + lr;
        af[mt] = *reinterpret_cast<const bf16x8*>(
            &a_lds[row * 128 + ((gc ^ (row & 7)) * 16)]);
      }
#pragma unroll
      for (int nt = 0; nt < 4; ++nt) {
        const int row = wn + nt * 16 + lr;
        bfr[nt] = *reinterpret_cast<const bf16x8*>(
            &b_lds[row * 128 + ((gc ^ (row & 7)) * 16)]);
      }
#pragma unroll
      for (int mt = 0; mt < 4; ++mt)
#pragma unroll
        for (int nt = 0; nt < 4; ++nt)
          acc[mt][nt] = mfma16(af[mt], bfr[nt], acc[mt][nt]);
    }
    __syncthreads();
  }

#pragma unroll
  for (int nt = 0; nt < 4; ++nt) {
    const int col = n0 + wn + nt * 16 + lr;
    const float bv = bias[col];
#pragma unroll
    for (int mt = 0; mt < 4; ++mt)
#pragma unroll
      for (int r = 0; r < 4; ++r) {
        const int row = m0 + wm + mt * 16 + hi * 4 + r;
        out[(size_t)row * DD + col] = f2bf(acc[mt][nt][r] + bv);
      }
  }
}

// ---------------- V gather+tiled-transpose ----------------
// VT2[b][kt64][cc][d][jj] = Vc[b][kt64*64 + cc*8 + jj][d]
__global__ void vtrans_kernel(const unsigned short* __restrict__ V,
                              const int* __restrict__ idx, const int* __restrict__ nbArr,
                              unsigned short* __restrict__ VT2) {
  __shared__ unsigned short t[64][72];
  const int b = blockIdx.z;
  const int kt = blockIdx.x;
  const int d0 = blockIdx.y * 64;
  const int tid = threadIdx.x;
  const int c = tid & 63, rg = tid >> 6;
  const int nb = nbArr[b];
#pragma unroll
  for (int i = 0; i < 16; ++i) {
    const int row = rg * 16 + i;
    const int s = kt * 64 + row;
    const int src = s < nb ? idx[b * SS + s] : 0;
    t[row][c] = V[((size_t)b * SS + src) * DD + d0 + c];
  }
  __syncthreads();
#pragma unroll
  for (int i = 0; i < 16; ++i) {
    const int ix = i * 256 + tid;
    const int jj = ix & 7;
    const int dl = (ix >> 3) & 63;
    const int cc = ix >> 9;
    VT2[(((size_t)(b * 32 + kt) * 8 + cc) * 512 + d0 + dl) * 8 + jj] =
        t[cc * 8 + jj][dl];
  }
}

// ---------------- flash attention, key-split-K, 2 blocks/CU ----------------
// Block: (b, qtile of 64, split sp). Split0 writes unnormalized A to Out,
// split1 to Apart (ws). (m,l) per row to mlpart.
__global__ __launch_bounds__(256, 2) void attn_kernel(
    const unsigned short* __restrict__ Q, const unsigned short* __restrict__ K,
    const unsigned short* __restrict__ VT2, const int* __restrict__ idx,
    const int* __restrict__ nbArr, float* __restrict__ Out,
    float* __restrict__ Apart, float* __restrict__ mlpart) {
  __shared__ unsigned char k_lds[32 * 1024];      // swizzled, no pad
  __shared__ unsigned char vt_lds[4 * 512 * 16];  // [cc][d][8 keys]
  __shared__ unsigned short pbuf[4][16][32];
  const int tid = threadIdx.x;
  const int w = tid >> 6, l = tid & 63, lr = l & 15, hi = l >> 4;
  const int bid = blockIdx.x;
  const int b = bid & 7;  // XCD-affinity: batch b -> XCD b
  const int qt = (bid >> 3) >> 1;
  const int sp = (bid >> 3) & 1;
  const int q0 = qt * 64 + w * 16;
  const float scale = 0.044194173824159216f;  // 1/sqrt(512)

  const int nb = nbArr[b];
  const int ntile = (nb + 31) >> 5;
  const int half = (ntile + 1) >> 1;
  const int lo = sp == 0 ? 0 : half;
  const int hi_t = sp == 0 ? half : ntile;

  const unsigned short* __restrict__ Qb = Q + (size_t)b * SS * DD;
  const unsigned short* __restrict__ Kb = K + (size_t)b * SS * DD;
  const unsigned short* __restrict__ Vb = VT2 + (size_t)b * SS * DD;
  const int* __restrict__ idxb = idx + b * SS;

  bf16x8 qf[16];
#pragma unroll
  for (int dk = 0; dk < 16; ++dk)
    qf[dk] = *reinterpret_cast<const bf16x8*>(
        &Qb[(size_t)(q0 + lr) * DD + dk * 32 + hi * 8]);

  f32x4 oacc[32];
#pragma unroll
  for (int i = 0; i < 32; ++i) oacc[i] = (f32x4){0.f, 0.f, 0.f, 0.f};
  float mrow[4], lrow[4];
#pragma unroll
  for (int r = 0; r < 4; ++r) {
    mrow[r] = -10000.0f;
    lrow[r] = 0.0f;
  }

  for (int t = lo; t < hi_t; ++t) {
    // ---- stage K (gather by idx, XOR-swizzled chunks) ----
#pragma unroll
    for (int r = 0; r < 8; ++r) {
      const int row = w * 8 + r;
      const int j = t * 32 + row;
      const int src = idxb[j];  // idx tail zeroed; masked later by j<nb
      const int ch = (l & 56) | ((l ^ row) & 7);
      gld16(Kb + (size_t)src * DD + ch * 8, &k_lds[row * 1024]);
    }
    // ---- stage V: wave w stages cc group (t&1)*4+w of the 64-key tile ----
    const size_t vbase = ((size_t)((t >> 1) * 8 + (t & 1) * 4 + w) * 512);
#pragma unroll
    for (int g = 0; g < 8; ++g)
      gld16(Vb + (vbase + g * 64 + l) * 8, &vt_lds[(w * 512 + g * 64) * 16]);
    __syncthreads();

    // ---- S = Q @ K^T (32 keys) ----
    f32x4 sacc[2];
#pragma unroll
    for (int nt = 0; nt < 2; ++nt) sacc[nt] = (f32x4){0.f, 0.f, 0.f, 0.f};
#pragma unroll
    for (int dk = 0; dk < 16; ++dk) {
#pragma unroll
      for (int nt = 0; nt < 2; ++nt) {
        const int row = nt * 16 + lr;
        const int c = dk * 4 + hi;
        bf16x8 bk = *reinterpret_cast<const bf16x8*>(
            &k_lds[row * 1024 + ((c & ~7) | ((c ^ row) & 7)) * 16]);
        sacc[nt] = mfma16(qf[dk], bk, sacc[nt]);
      }
    }

    float s[2][4];
#pragma unroll
    for (int nt = 0; nt < 2; ++nt) {
      const int j = t * 32 + nt * 16 + lr;
      const bool ok = j < nb;
#pragma unroll
      for (int r = 0; r < 4; ++r)
        s[nt][r] = ok ? sacc[nt][r] * scale : -10000.0f;
    }

    // ---- online softmax ----
    float mnew[4], alpha[4];
#pragma unroll
    for (int r = 0; r < 4; ++r) {
      float mx = fmaxf(s[0][r], s[1][r]);
#pragma unroll
      for (int off = 1; off < 16; off <<= 1) mx = fmaxf(mx, __shfl_xor(mx, off));
      mnew[r] = fmaxf(mrow[r], mx);
      alpha[r] = __expf(mrow[r] - mnew[r]);
      mrow[r] = mnew[r];
    }
    float rs[4] = {0.f, 0.f, 0.f, 0.f};
#pragma unroll
    for (int nt = 0; nt < 2; ++nt)
#pragma unroll
      for (int r = 0; r < 4; ++r) {
        float p = __expf(s[nt][r] - mnew[r]);
        s[nt][r] = p;
        rs[r] += p;
      }
#pragma unroll
    for (int r = 0; r < 4; ++r) {
      float tt = rs[r];
#pragma unroll
      for (int off = 1; off < 16; off <<= 1) tt += __shfl_xor(tt, off);
      lrow[r] = lrow[r] * alpha[r] + tt;
    }

    // ---- P relayout C->A via per-wave LDS ----
#pragma unroll
    for (int nt = 0; nt < 2; ++nt)
#pragma unroll
      for (int r = 0; r < 4; ++r)
        pbuf[w][hi * 4 + r][nt * 16 + lr] = f2bf(s[nt][r]);
    bf16x8 pf = *reinterpret_cast<const bf16x8*>(&pbuf[w][lr][hi * 8]);

    // ---- lazy O rescale: skip when all alphas == 1 across the wave ----
    const float aprod = alpha[0] * alpha[1] * alpha[2] * alpha[3];
    unsigned long long bal = __ballot(aprod == 1.0f);
    if (bal != ~0ull) {
#pragma unroll
      for (int nt2 = 0; nt2 < 32; ++nt2)
#pragma unroll
        for (int r = 0; r < 4; ++r) oacc[nt2][r] *= alpha[r];
    }
    // ---- O += P @ V ----
#pragma unroll
    for (int nt2 = 0; nt2 < 32; ++nt2) {
      bf16x8 v0 = *reinterpret_cast<const bf16x8*>(
          &vt_lds[(hi * 512 + nt2 * 16 + lr) * 16]);
      oacc[nt2] = mfma16(pf, v0, oacc[nt2]);
    }
    __syncthreads();
  }

  // ---- epilogue: write unnormalized A + (m,l) per row ----
  float* Ap = sp == 0 ? Out : Apart;
#pragma unroll
  for (int nt2 = 0; nt2 < 32; ++nt2)
#pragma unroll
    for (int r = 0; r < 4; ++r)
      Ap[((size_t)b * SS + q0 + hi * 4 + r) * DD + nt2 * 16 + lr] = oacc[nt2][r];
  if (lr == 0) {
#pragma unroll
    for (int r = 0; r < 4; ++r) {
      const size_t row = (size_t)sp * MM + b * SS + q0 + hi * 4 + r;
      mlpart[row * 2 + 0] = mrow[r];
      mlpart[row * 2 + 1] = lrow[r];
    }
  }
}

// ---------------- combine: in-place merge split0 (in Out) + split1 (Apart) ----------------
__global__ void combine_kernel(float* __restrict__ Out, const float* __restrict__ Apart,
                               const float* __restrict__ mlpart) {
  const int gid = blockIdx.x * 256 + threadIdx.x;  // over MM*DD/4
  const int row = gid >> 7;
  const float m1 = mlpart[(size_t)row * 2 + 0];
  const float l1 = mlpart[(size_t)row * 2 + 1];
  const float m2 = mlpart[((size_t)MM + row) * 2 + 0];
  const float l2 = mlpart[((size_t)MM + row) * 2 + 1];
  const float m = fmaxf(m1, m2);
  const float w1 = __expf(m1 - m), w2 = __expf(m2 - m);
  const float inv = 1.0f / (w1 * l1 + w2 * l2);
  f32x4 a1 = reinterpret_cast<f32x4*>(Out)[gid];
  f32x4 a2 = reinterpret_cast<const f32x4*>(Apart)[gid];
  f32x4 o;
#pragma unroll
  for (int e = 0; e < 4; ++e) o[e] = (w1 * a1[e] + w2 * a2[e]) * inv;
  reinterpret_cast<f32x4*>(Out)[gid] = o;
}

extern "C" void kernel_launch(void* const* d_in, const int* in_sizes, int n_in,
                              void* d_out, int out_size, void* d_ws, size_t ws_size,
                              hipStream_t stream) {
  const float* x = (const float*)d_in[0];
  const int* mask = (const int*)d_in[1];
  const float* Wq = (const float*)d_in[2];
  const float* bq = (const float*)d_in[3];
  const float* Wk = (const float*)d_in[4];
  const float* bk = (const float*)d_in[5];
  const float* Wv = (const float*)d_in[6];
  const float* bv = (const float*)d_in[7];
  float* out = (float*)d_out;

  // ws layout (max ~82.4 MB, matching the R3-proven footprint):
  //   0-16   Qb          (live through attn)
  //   16-32  Kb          (live through attn)
  //   32-48  VT2b        (live through attn)
  //   48-64  Xb          (dead after qkv_gemm)
  //   64-80  Vb          (dead after vtrans)
  //   48-80  Apart       (split1 partial, 32 MB — aliases Xb+Vb, both dead)
  //   80-81.5 weights    (dead after qkv_gemm)
  //   82+    idx (64KB), nbArr, mlpart (256KB)
  char* ws = (char*)d_ws;
  const size_t MB = 1024 * 1024;
  unsigned short* Qb = (unsigned short*)(ws);
  unsigned short* Kb = (unsigned short*)(ws + 16 * MB);
  unsigned short* VT2b = (unsigned short*)(ws + 32 * MB);
  unsigned short* Xb = (unsigned short*)(ws + 48 * MB);
  unsigned short* Vb = (unsigned short*)(ws + 64 * MB);
  float* Apart = (float*)(ws + 48 * MB);
  unsigned short* Wqb = (unsigned short*)(ws + 80 * MB);
  unsigned short* Wkb = Wqb + 512 * 512;
  unsigned short* Wvb = Wkb + 512 * 512;
  int* idx = (int*)(ws + 82 * MB);
  int* nbArr = (int*)(ws + 82 * MB + 65536);
  float* mlpart = (float*)(ws + 82 * MB + 128 * 1024);

  cvt_bf16_kernel<<<8192, 256, 0, stream>>>(x, Xb, (MM * DD) / 4);
  cvt_w3_kernel<<<dim3(256, 3), 256, 0, stream>>>(Wq, Wk, Wv, Wqb, Wkb, Wvb);
  mask_scan_kernel<<<BB, 256, 0, stream>>>(mask, idx, nbArr);

  qkv_gemm_kernel<<<dim3(MM / 128, 12), 256, 0, stream>>>(
      Xb, Wqb, Wkb, Wvb, bq, bk, bv, Qb, Kb, Vb);

  vtrans_kernel<<<dim3(SS / 64, DD / 64, BB), 256, 0, stream>>>(Vb, idx, nbArr, VT2b);

  attn_kernel<<<512, 256, 0, stream>>>(Qb, Kb, VT2b, idx, nbArr, out, Apart, mlpart);

  combine_kernel<<<(MM * DD / 4) / 256, 256, 0, stream>>>(out, Apart, mlpart);
}